// Round 7
// baseline (133.452 us; speedup 1.0000x reference)
//
#include <hip/hip_runtime.h>

// B=65536, Q=128, S=8, U=32
// out[b,q] = b2[q] + sum_u elu(b1[q,u] + sum_s x[b,q,s]*W1[q,s,u]) * W2[q,u]
//
// R7 = R6 (MFMA GEMM1) with the occupancy cap removed:
//   __launch_bounds__(256, 8): VGPR budget 64 (kernel uses ~52) -> up to
//   32 waves/CU; grid = 2048 blocks = 8 blocks/CU at 8 KB LDS. TLP hides the
//   per-qi L2 weight-load + MFMA + ELU latency chain that 4 waves/EU couldn't.
#define Q    128
#define S    8
#define U    32
#define QCH  16            // q per x-stage chunk
#define NCH  (Q / QCH)     // 8 chunks
#define ROWS 32            // rows per block = MFMA N
#define WQ   4             // q per wave per chunk (4 waves)

typedef __attribute__((ext_vector_type(8)))  __bf16 bf16x8;
typedef __attribute__((ext_vector_type(16))) float  f32x16;

__device__ inline unsigned short f2bf(float f) {   // RTN f32->bf16
    unsigned int u = __float_as_uint(f);
    u += 0x7FFF + ((u >> 16) & 1);
    return (unsigned short)(u >> 16);
}

// ---- prep: W1T[q][u][s] bf16 ; b1F/w2F[q][half][reg] f32 in C-reg order ----
__global__ void prep_kernel(const float* __restrict__ W1, const float* __restrict__ b1,
                            const float* __restrict__ W2,
                            unsigned short* __restrict__ W1T,
                            float* __restrict__ b1F, float* __restrict__ w2F)
{
    const int q = blockIdx.x, t = threadIdx.x;     // 128 blocks x 256 threads
    const int u = t & 31, s = t >> 5;
    W1T[(q * 32 + u) * 8 + s] = f2bf(W1[(q * 8 + s) * 32 + u]);
    if (t < 32) {
        int reg = t & 15, hh = t >> 4;
        int uu  = (reg & 3) + 8 * (reg >> 2) + 4 * hh;   // verified C/D row map
        b1F[(q * 2 + hh) * 16 + reg] = b1[q * 32 + uu];
        w2F[(q * 2 + hh) * 16 + reg] = W2[q * 32 + uu];
    }
}

__global__ __launch_bounds__(256, 8)   // min 8 waves/EU -> VGPR budget 64, full occupancy
void divenc_mfma(const float* __restrict__ x,
                 const unsigned short* __restrict__ W1T,
                 const float* __restrict__ b1F,
                 const float* __restrict__ w2F,
                 const float* __restrict__ b2,
                 float* __restrict__ out, int B)
{
    __shared__ unsigned short xs[QCH * ROWS * 8];   // 8 KB bf16, 16B-XOR-swizzled

    const int t     = threadIdx.x;
    const int lane  = t & 63;
    const int wv    = __builtin_amdgcn_readfirstlane(t >> 6);
    const int rbase = blockIdx.x * ROWS;
    const int rmax  = B - 1;
    const int bl    = lane & 31;             // b-row (as B col) / u (as A row)
    const int h     = lane >> 5;
    const unsigned int zmask = (lane < 32) ? 0xFFFFFFFFu : 0u;

    #pragma unroll 1
    for (int ch = 0; ch < NCH; ++ch) {
        const int q0 = ch * QCH;
        __syncthreads();                      // protect xs reuse
        // ---- stage x chunk: 32 rows x 16 q x 8 s, f32->bf16, swizzled ----
        #pragma unroll
        for (int k = 0; k < 4; ++k) {
            int idx = t + k * 256;            // 0..1023 float4s
            int row = idx >> 5, f4 = idx & 31;
            int r = rbase + row; if (r > rmax) r = rmax;
            float4 v = *(const float4*)(x + (size_t)r * (Q * S) + q0 * S + f4 * 4);
            int qr = f4 >> 1, sh = f4 & 1;
            // byte addr: qr*512 + (row*16 ^ ((qr&7)<<4)) + sh*8
            // write banks 2-way (free); read swizzle term wave-uniform -> conflict-free
            int ub = qr * 512 + ((row * 16) ^ ((qr & 7) << 4)) + sh * 8;
            ushort4 bv;
            bv.x = f2bf(v.x); bv.y = f2bf(v.y); bv.z = f2bf(v.z); bv.w = f2bf(v.w);
            *(ushort4*)((char*)xs + ub) = bv;
        }
        __syncthreads();

        // ---- compute: wave wv handles q = q0 + wv*4 + qi ----
        #pragma unroll 1
        for (int qi = 0; qi < WQ; ++qi) {
            const int qr = wv * WQ + qi;      // uniform per wave
            const int q  = q0 + qr;

            // B-frag: x[row=bl][s] ; lanes>=32 are k=8..15 -> zero
            uint4 bx = *(const uint4*)((const char*)xs
                         + qr * 512 + ((bl * 16) ^ ((qr & 7) << 4)));
            bx.x &= zmask; bx.y &= zmask; bx.z &= zmask; bx.w &= zmask;

            // A-frag: W1T[q][u=bl][s0..7] (upper lanes duplicate low; B=0 kills it)
            uint4 ax = *(const uint4*)(W1T + ((size_t)q * 32 + bl) * 8);

            // C-in = b1 in register order (64B aligned)
            f32x16 cin = *(const f32x16*)(b1F + ((size_t)q * 2 + h) * 16);

            f32x16 cc = __builtin_amdgcn_mfma_f32_32x32x16_bf16(
                __builtin_bit_cast(bf16x8, ax), __builtin_bit_cast(bf16x8, bx),
                cin, 0, 0, 0);

            f32x16 wr = *(const f32x16*)(w2F + ((size_t)q * 2 + h) * 16);

            float acc = 0.f;
#define EL(I) { float v_ = cc[I]; float e_ = __expf(fminf(v_, 0.f)) - 1.f;   \
                acc = fmaf(fmaxf(v_, e_), wr[I], acc); }
            EL(0)  EL(1)  EL(2)  EL(3)  EL(4)  EL(5)  EL(6)  EL(7)
            EL(8)  EL(9)  EL(10) EL(11) EL(12) EL(13) EL(14) EL(15)
#undef EL
            acc += __shfl_xor(acc, 32);       // combine u-halves

            const int r = rbase + bl;
            if (lane < 32 && r < B)
                out[(size_t)r * Q + q] = acc + b2[q];
        }
    }
}

extern "C" void kernel_launch(void* const* d_in, const int* in_sizes, int n_in,
                              void* d_out, int out_size, void* d_ws, size_t ws_size,
                              hipStream_t stream) {
    const float* x  = (const float*)d_in[0];
    const float* W1 = (const float*)d_in[1];
    const float* b1 = (const float*)d_in[2];
    const float* W2 = (const float*)d_in[3];
    const float* b2 = (const float*)d_in[4];
    float* out = (float*)d_out;

    unsigned short* W1T = (unsigned short*)d_ws;                 // 64 KB
    float*          b1F = (float*)((char*)d_ws + 65536);         // 16 KB
    float*          w2F = (float*)((char*)d_ws + 65536 + 16384); // 16 KB

    const int B = in_sizes[0] / (Q * S);

    hipLaunchKernelGGL(prep_kernel, dim3(Q), dim3(256), 0, stream,
                       W1, b1, W2, W1T, b1F, w2F);
    hipLaunchKernelGGL(divenc_mfma, dim3((B + ROWS - 1) / ROWS), dim3(256), 0, stream,
                       x, W1T, b1F, w2F, b2, out, B);
}

// Round 9
// 111.908 us; speedup vs baseline: 1.1925x; 1.1925x over previous
//
#include <hip/hip_runtime.h>

// B=65536, Q=128, S=8, U=32
// out[b,q] = b2[q] + sum_u elu(b1[q,u] + sum_s x[b,q,s]*W1[q,s,u]) * W2[q,u]
//
// R9 = R8 with the bf16 pack done via inline-asm v_cvt_pk_bf16_f32
// (no builtin on gfx950; __hip_bfloat162 isn't bit_cast-able).
//  - ROWS=64: two row-tiles per qi share A-frag/C-in/W2/addressing/barriers
//  - packed-f32 ELU epilogue (pk min/mul/sub/max/fma + raw v_exp)
//  - cvt_pk bf16 staging, 272B-padded LDS (17*l mod 32 permutation: read
//    conflict-free, write 2-way = free), zero-page instead of zmask
#define Q    128
#define S    8
#define U    32
#define QCH  16            // q per x-stage chunk
#define NCH  (Q / QCH)     // 8 chunks
#define ROWS 64            // rows per block = 2 MFMA row-tiles
#define WQ   4             // q per wave per chunk (4 waves)
#define RSTRIDE 272        // LDS row stride bytes (17*16)
#define ZOFF (ROWS * RSTRIDE)   // zero-page offset

typedef __attribute__((ext_vector_type(8)))  __bf16 bf16x8;
typedef __attribute__((ext_vector_type(16))) float  f32x16;
typedef __attribute__((ext_vector_type(2)))  float  f32x2;

__device__ inline unsigned short f2bf(float f) {   // RTN f32->bf16 (prep only)
    unsigned int u = __float_as_uint(f);
    u += 0x7FFF + ((u >> 16) & 1);
    return (unsigned short)(u >> 16);
}

__device__ inline unsigned int cvt_pk_bf16(float lo, float hi) {
    unsigned int r;
    asm("v_cvt_pk_bf16_f32 %0, %1, %2" : "=v"(r) : "v"(lo), "v"(hi));
    return r;
}

// ---- prep: W1T[q][u][s] bf16 ; b1F/w2F[q][half][reg] f32 in C-reg order ----
__global__ void prep_kernel(const float* __restrict__ W1, const float* __restrict__ b1,
                            const float* __restrict__ W2,
                            unsigned short* __restrict__ W1T,
                            float* __restrict__ b1F, float* __restrict__ w2F)
{
    const int q = blockIdx.x, t = threadIdx.x;     // 128 blocks x 256 threads
    const int u = t & 31, s = t >> 5;
    W1T[(q * 32 + u) * 8 + s] = f2bf(W1[(q * 8 + s) * 32 + u]);
    if (t < 32) {
        int reg = t & 15, hh = t >> 4;
        int uu  = (reg & 3) + 8 * (reg >> 2) + 4 * hh;   // verified C/D row map
        b1F[(q * 2 + hh) * 16 + reg] = b1[q * 32 + uu];
        w2F[(q * 2 + hh) * 16 + reg] = W2[q * 32 + uu];
    }
}

__global__ __launch_bounds__(256, 4)   // VGPR budget 128 (don't strangle ILP)
void divenc_mfma(const float* __restrict__ x,
                 const unsigned short* __restrict__ W1T,
                 const float* __restrict__ b1F,
                 const float* __restrict__ w2F,
                 const float* __restrict__ b2,
                 float* __restrict__ out, int B)
{
    __shared__ __align__(16) unsigned char xs[ROWS * RSTRIDE + 16];  // ~17.4 KB

    const int t     = threadIdx.x;
    const int lane  = t & 63;
    const int wv    = __builtin_amdgcn_readfirstlane(t >> 6);
    const int rbase = blockIdx.x * ROWS;
    const int rmax  = B - 1;
    const int bl    = lane & 31;             // b-row (tile) / u (A row)
    const int h     = lane >> 5;
    const bool lo   = (lane < 32);

    if (t == 0) *(uint4*)(xs + ZOFF) = uint4{0, 0, 0, 0};   // zero page

    const f32x2 k_log2e = 1.44269504088896f;
    const f32x2 zero2   = 0.0f;
    const f32x2 one2    = 1.0f;

    #pragma unroll 1
    for (int ch = 0; ch < NCH; ++ch) {
        const int q0 = ch * QCH;
        __syncthreads();                      // protects xs reuse (+ zero page, it=0)
        // ---- stage x: 64 rows x 16 q x 8 s -> bf16, cvt_pk, padded rows ----
        #pragma unroll
        for (int k = 0; k < 4; ++k) {
            int idx = t + k * 256;            // 0..1023 units of 8 floats
            int row = idx >> 4, qr = idx & 15;
            int r = rbase + row; if (r > rmax) r = rmax;
            const float4* p = (const float4*)(x + (size_t)r * (Q * S) + (size_t)(q0 + qr) * S);
            float4 a = p[0], b = p[1];
            uint4 w;
            w.x = cvt_pk_bf16(a.x, a.y);
            w.y = cvt_pk_bf16(a.z, a.w);
            w.z = cvt_pk_bf16(b.x, b.y);
            w.w = cvt_pk_bf16(b.z, b.w);
            *(uint4*)(xs + row * RSTRIDE + qr * 16) = w;
        }
        __syncthreads();

        // ---- compute: wave wv handles q = q0 + wv*4 + qi, 2 row-tiles each ----
        #pragma unroll 1
        for (int qi = 0; qi < WQ; ++qi) {
            const int qr = wv * WQ + qi;      // uniform per wave
            const int q  = q0 + qr;

            // B-frags: rows bl / bl+32; lanes>=32 read the zero page (k=8..15 = 0)
            const int xoff = bl * RSTRIDE + qr * 16;
            uint4 bx0 = *(const uint4*)(xs + (lo ? xoff                : ZOFF));
            uint4 bx1 = *(const uint4*)(xs + (lo ? xoff + 32 * RSTRIDE : ZOFF));

            // A-frag: W1T[q][u=bl][s0..7] (upper lanes duplicate; B=0 kills k>=8)
            uint4 ax = *(const uint4*)(W1T + ((size_t)q * 32 + bl) * 8);

            // C-in = b1 in register order
            f32x16 cin = *(const f32x16*)(b1F + ((size_t)q * 2 + h) * 16);

            f32x16 cc0 = __builtin_amdgcn_mfma_f32_32x32x16_bf16(
                __builtin_bit_cast(bf16x8, ax), __builtin_bit_cast(bf16x8, bx0),
                cin, 0, 0, 0);
            f32x16 cc1 = __builtin_amdgcn_mfma_f32_32x32x16_bf16(
                __builtin_bit_cast(bf16x8, ax), __builtin_bit_cast(bf16x8, bx1),
                cin, 0, 0, 0);

            f32x16 wr = *(const f32x16*)(w2F + ((size_t)q * 2 + h) * 16);
            const float b2v = b2[q];

            // ---- packed ELU + GEMM2: per pair {pk_min,pk_mul,2xexp,pk_sub,pk_max,pk_fma}
#define EL2(CC, J, ACC) {                                                            \
        f32x2 h2; h2.x = CC[2*(J)]; h2.y = CC[2*(J)+1];                              \
        f32x2 w2v; w2v.x = wr[2*(J)]; w2v.y = wr[2*(J)+1];                           \
        f32x2 m = __builtin_elementwise_min(h2, zero2) * k_log2e;                    \
        f32x2 e; e.x = __builtin_amdgcn_exp2f(m.x); e.y = __builtin_amdgcn_exp2f(m.y); \
        e = e - one2;                                                                \
        f32x2 r_ = __builtin_elementwise_max(h2, e);                                 \
        ACC = __builtin_elementwise_fma(r_, w2v, ACC); }

            f32x2 acc0 = 0.0f, acc1 = 0.0f;
            EL2(cc0, 0, acc0) EL2(cc0, 1, acc0) EL2(cc0, 2, acc0) EL2(cc0, 3, acc0)
            EL2(cc0, 4, acc0) EL2(cc0, 5, acc0) EL2(cc0, 6, acc0) EL2(cc0, 7, acc0)
            EL2(cc1, 0, acc1) EL2(cc1, 1, acc1) EL2(cc1, 2, acc1) EL2(cc1, 3, acc1)
            EL2(cc1, 4, acc1) EL2(cc1, 5, acc1) EL2(cc1, 6, acc1) EL2(cc1, 7, acc1)
#undef EL2

            float a0 = acc0.x + acc0.y;
            float a1 = acc1.x + acc1.y;
            a0 += __shfl_xor(a0, 32);         // combine u-halves
            a1 += __shfl_xor(a1, 32);

            const int r0 = rbase + bl, r1 = r0 + 32;
            if (lo && r0 < B) out[(size_t)r0 * Q + q] = a0 + b2v;
            if (lo && r1 < B) out[(size_t)r1 * Q + q] = a1 + b2v;
        }
    }
}

extern "C" void kernel_launch(void* const* d_in, const int* in_sizes, int n_in,
                              void* d_out, int out_size, void* d_ws, size_t ws_size,
                              hipStream_t stream) {
    const float* x  = (const float*)d_in[0];
    const float* W1 = (const float*)d_in[1];
    const float* b1 = (const float*)d_in[2];
    const float* W2 = (const float*)d_in[3];
    const float* b2 = (const float*)d_in[4];
    float* out = (float*)d_out;

    unsigned short* W1T = (unsigned short*)d_ws;                 // 64 KB
    float*          b1F = (float*)((char*)d_ws + 65536);         // 16 KB
    float*          w2F = (float*)((char*)d_ws + 65536 + 16384); // 16 KB

    const int B = in_sizes[0] / (Q * S);

    hipLaunchKernelGGL(prep_kernel, dim3(Q), dim3(256), 0, stream,
                       W1, b1, W2, W1T, b1F, w2F);
    hipLaunchKernelGGL(divenc_mfma, dim3((B + ROWS - 1) / ROWS), dim3(256), 0, stream,
                       x, W1T, b1F, w2F, b2, out, B);
}